// Round 1
// baseline (314.810 us; speedup 1.0000x reference)
//
#include <hip/hip_runtime.h>
#include <stdint.h>

#define F0    2048      // base input features (= GEMM K)
#define EROWS 512       // embed rows per level
#define NOUT  2048      // output features (= GEMM N)
#define MROWS 8192      // batch (= GEMM M)

typedef __attribute__((ext_vector_type(8))) short bf16x8;
typedef __attribute__((ext_vector_type(4))) float f32x4;
typedef __attribute__((ext_vector_type(8))) unsigned short u16x8;

typedef const __attribute__((address_space(1))) unsigned char ga_t;
typedef __attribute__((address_space(3))) unsigned char lds_t;

__device__ __forceinline__ void async_load16(const void* g, void* l) {
  __builtin_amdgcn_global_load_lds((ga_t*)g, (lds_t*)l, 16, 0, 0);
}

__device__ __forceinline__ unsigned short f2bf(float f) {
  unsigned int u = __builtin_bit_cast(unsigned int, f);
  u += 0x7fffu + ((u >> 16) & 1u);   // round-to-nearest-even
  return (unsigned short)(u >> 16);
}

// ---------------------------------------------------------------------------
// Expand one sparse COO level into a dense [n_rows x F0] matrix over x-space.
// Dsrc = base of previously expanded rows (D0;D1;D2 contiguous); col c >= F0
// refers to Dsrc row (c - F0). One block per output row.
// ---------------------------------------------------------------------------
__global__ __launch_bounds__(256) void expand_kernel(
    const int* __restrict__ rows, const int* __restrict__ cols,
    const float* __restrict__ vals, int nnz,
    const float* __restrict__ Dsrc, float* __restrict__ Dout)
{
  const int r = blockIdx.x;
  const int tid = threadIdx.x;
  __shared__ float acc[F0];
  __shared__ int s_col[512];
  __shared__ float s_val[512];
  __shared__ int s_cnt;

  for (int j = tid; j < F0; j += 256) acc[j] = 0.f;
  if (tid == 0) s_cnt = 0;
  __syncthreads();

  // Phase 1: collect this row's nnz into LDS
  for (int k = tid; k < nnz; k += 256) {
    if (rows[k] == r) {
      int idx = atomicAdd(&s_cnt, 1);
      if (idx < 512) { s_col[idx] = cols[k]; s_val[idx] = vals[k]; }
    }
  }
  __syncthreads();
  int cnt = s_cnt; if (cnt > 512) cnt = 512;

  // Phase 2a: direct entries (c < F0). Duplicates possible -> LDS atomics.
  for (int i = tid; i < cnt; i += 256) {
    int c = s_col[i];
    if (c < F0) atomicAdd(&acc[c], s_val[i]);
  }
  __syncthreads();

  // Phase 2b: indirect entries -> block-wide AXPY with prior level's row.
  for (int i = 0; i < cnt; ++i) {
    int c = s_col[i];
    if (c >= F0) {
      const float* src = Dsrc + (size_t)(c - F0) * F0;
      float v = s_val[i];
      for (int j = tid; j < F0; j += 256) acc[j] += v * src[j];
    }
  }
  __syncthreads();

  float* dst = Dout + (size_t)r * F0;
  for (int j = tid; j < F0; j += 256) dst[j] = acc[j];
}

// ---------------------------------------------------------------------------
// fp32 -> bf16 cast, 8 elements per thread
// ---------------------------------------------------------------------------
__global__ __launch_bounds__(256) void cvt_bf16_kernel(
    const float* __restrict__ in, unsigned short* __restrict__ out, int n8)
{
  int i = blockIdx.x * 256 + threadIdx.x;
  if (i >= n8) return;
  const float4* p = (const float4*)in;
  float4 a = p[i * 2], b = p[i * 2 + 1];
  u16x8 o;
  o[0] = f2bf(a.x); o[1] = f2bf(a.y); o[2] = f2bf(a.z); o[3] = f2bf(a.w);
  o[4] = f2bf(b.x); o[5] = f2bf(b.y); o[6] = f2bf(b.z); o[7] = f2bf(b.w);
  ((u16x8*)out)[i] = o;
}

// ---------------------------------------------------------------------------
// C[m,n] = sum_k A[m,k] * B[n,k]   (A: MROWSxK bf16, B: NOUTxK bf16, C fp32)
// 128x128 tile, BK=64, 4 waves (2x2 of 64x64), global_load_lds width=16,
// XOR-swizzled LDS (chunk c stored at slot c ^ (row&7)) to balance banks.
// ---------------------------------------------------------------------------
__global__ __launch_bounds__(256) void gemm_bt_kernel(
    const unsigned short* __restrict__ A, const unsigned short* __restrict__ B,
    float* __restrict__ C)
{
  constexpr int K = F0;
  constexpr int N = NOUT;
  __shared__ __align__(16) unsigned short sA[128 * 64];
  __shared__ __align__(16) unsigned short sB[128 * 64];

  const int tid  = threadIdx.x;
  const int lane = tid & 63;
  const int w    = tid >> 6;
  const int wm   = (w & 1) * 64;
  const int wn   = (w >> 1) * 64;
  const int mm   = lane & 15;     // row-within-16 for frag loads
  const int g    = lane >> 4;     // k-group
  const int bm   = blockIdx.y;
  const int bn   = blockIdx.x;

  const unsigned short* Ag = A + (size_t)bm * 128 * K;
  const unsigned short* Bg = B + (size_t)bn * 128 * K;

  int su[4], srow[4], scg[4];
  for (int i = 0; i < 4; ++i) {
    int u = i * 256 + tid;        // 0..1023 : (row = u>>3, slot = u&7)
    su[i]   = u;
    srow[i] = u >> 3;
    scg[i]  = (u & 7) ^ ((u >> 3) & 7);   // global chunk stored at this slot
  }

  f32x4 acc[4][4];
  for (int a = 0; a < 4; ++a)
    for (int b = 0; b < 4; ++b) acc[a][b] = (f32x4)0.f;

  for (int k0 = 0; k0 < K; k0 += 64) {
    for (int i = 0; i < 4; ++i) {
      async_load16(Ag + (size_t)srow[i] * K + k0 + scg[i] * 8, sA + su[i] * 8);
      async_load16(Bg + (size_t)srow[i] * K + k0 + scg[i] * 8, sB + su[i] * 8);
    }
    __syncthreads();

    for (int ks = 0; ks < 2; ++ks) {
      bf16x8 af[4], bf[4];
      for (int t = 0; t < 4; ++t) {
        int mrow = wm + t * 16 + mm;
        int sa   = (ks * 4 + g) ^ (mrow & 7);
        af[t] = *(const bf16x8*)(sA + mrow * 64 + sa * 8);
        int nrow = wn + t * 16 + mm;
        int sb   = (ks * 4 + g) ^ (nrow & 7);
        bf[t] = *(const bf16x8*)(sB + nrow * 64 + sb * 8);
      }
      for (int tm = 0; tm < 4; ++tm)
        for (int tn = 0; tn < 4; ++tn)
          acc[tm][tn] = __builtin_amdgcn_mfma_f32_16x16x32_bf16(
              af[tm], bf[tn], acc[tm][tn], 0, 0, 0);
    }
    __syncthreads();
  }

  for (int tm = 0; tm < 4; ++tm) {
    int rowb = bm * 128 + wm + tm * 16 + g * 4;
    for (int tn = 0; tn < 4; ++tn) {
      int col = bn * 128 + wn + tn * 16 + mm;
      for (int r = 0; r < 4; ++r)
        C[(size_t)(rowb + r) * N + col] = acc[tm][tn][r];
    }
  }
}

// ---------------------------------------------------------------------------
extern "C" void kernel_launch(void* const* d_in, const int* in_sizes, int n_in,
                              void* d_out, int out_size, void* d_ws, size_t ws_size,
                              hipStream_t stream)
{
  const float* x   = (const float*)d_in[0];
  const int*   er0 = (const int*)d_in[1];
  const int*   ec0 = (const int*)d_in[2];
  const float* ev0 = (const float*)d_in[3];
  const int*   er1 = (const int*)d_in[4];
  const int*   ec1 = (const int*)d_in[5];
  const float* ev1 = (const float*)d_in[6];
  const int*   er2 = (const int*)d_in[7];
  const int*   ec2 = (const int*)d_in[8];
  const float* ev2 = (const float*)d_in[9];
  const int*   mr  = (const int*)d_in[10];
  const int*   mc  = (const int*)d_in[11];
  const float* mv  = (const float*)d_in[12];
  const int nnz_e0 = in_sizes[1];
  const int nnz_e1 = in_sizes[4];
  const int nnz_e2 = in_sizes[7];
  const int nnz_m  = in_sizes[10];

  // workspace layout (fp32 elements)
  float* D  = (float*)d_ws;                       // [3*EROWS][F0]  (12 MB)
  float* Mf = D + (size_t)3 * EROWS * F0;         // [NOUT][F0]     (16 MB)
  unsigned short* Mb = (unsigned short*)(Mf + (size_t)NOUT * F0);  // bf16 (8 MB)
  unsigned short* Ab = Mb + (size_t)NOUT * F0;    // x bf16         (32 MB)

  // 1) expand chain into x-space (levels depend on previous -> serialized)
  hipLaunchKernelGGL(expand_kernel, dim3(EROWS), dim3(256), 0, stream,
                     er0, ec0, ev0, nnz_e0, D, D);
  hipLaunchKernelGGL(expand_kernel, dim3(EROWS), dim3(256), 0, stream,
                     er1, ec1, ev1, nnz_e1, D, D + (size_t)EROWS * F0);
  hipLaunchKernelGGL(expand_kernel, dim3(EROWS), dim3(256), 0, stream,
                     er2, ec2, ev2, nnz_e2, D, D + (size_t)2 * EROWS * F0);
  hipLaunchKernelGGL(expand_kernel, dim3(NOUT), dim3(256), 0, stream,
                     mr, mc, mv, nnz_m, D, Mf);

  // 2) casts to bf16
  {
    int n8 = (NOUT * F0) / 8;
    hipLaunchKernelGGL(cvt_bf16_kernel, dim3(n8 / 256), dim3(256), 0, stream,
                       Mf, Mb, n8);
  }
  {
    int n8 = (MROWS * F0) / 8;
    hipLaunchKernelGGL(cvt_bf16_kernel, dim3(n8 / 256), dim3(256), 0, stream,
                       x, Ab, n8);
  }

  // 3) out = x @ M^T   (grid: 16 n-blocks x 64 m-blocks)
  hipLaunchKernelGGL(gemm_bt_kernel, dim3(NOUT / 128, MROWS / 128), dim3(256),
                     0, stream, Ab, Mb, (float*)d_out);
}